// Round 8
// baseline (202.723 us; speedup 1.0000x reference)
//
#include <hip/hip_runtime.h>
#include <hip/hip_bf16.h>

// Char-LSTM via MFMA, round 8.
// Round-7 diagnosis: VALUBusy 33% with correct issue-count model => 2/3 of wall
// is in-order dependency stalls in the cell-by-cell activation chains (7-deep
// trans chains, ~8cyc bubble per trans, only 2 waves/SIMD to cover).
// Fix: BATCHED activations — per half-step, same-op batches over 8 independent
// cells (32 exp2 | 8 rcp | 8 rcp | 8 exp2 | 8 rcp) issue back-to-back with ~0
// bubbles. Costs registers (~230 VGPR, launch_bounds(256,2) allows 256).
// Also: B ds_read moved to end-of-step (LDS latency hidden under next MFMAs),
// rolling 2-step char prefetch. Schedule unchanged: 2048 uniform waves
// (complementary pair g, 4095-g => ~17 steps/wave, SIMD-balance guaranteed).

#define VOCAB 100
#define E     32
#define NW    65536
#define MAXL  16
#define NGRP  4096   // NW/16

typedef __bf16 bf16x8 __attribute__((ext_vector_type(8)));
typedef float  f32x4  __attribute__((ext_vector_type(4)));
typedef unsigned short ushort_t;
typedef unsigned int uint_t;

#define LOG2E    1.4426950408889634f
#define TWOLOG2E 2.8853900817779268f

__device__ __forceinline__ ushort_t f2bf(float x) {
    union { __hip_bfloat16 b; ushort_t u; } cv;
    cv.b = __float2bfloat16(x);
    return cv.u;
}
__device__ __forceinline__ float exp2_hw(float x) { return __builtin_amdgcn_exp2f(x); }
__device__ __forceinline__ float rcp_hw(float x)  { return __builtin_amdgcn_rcpf(x); }

// ---- K1: xtab [100][256] f32 (scaled), Wb [256][64] bf16 (scaled), hist bh[256][16] ----
__global__ void prep_all(const float* __restrict__ emb, const float* __restrict__ Wih,
                         const float* __restrict__ Whh, const float* __restrict__ bih,
                         const float* __restrict__ bhh, const int* __restrict__ lengths,
                         float* __restrict__ xtab, ushort_t* __restrict__ Wb,
                         int* __restrict__ bh) {
    int bid = blockIdx.x;
    if (bid < VOCAB) {                         // xtab row: g = q*64+u (torch row order)
        int ch = bid, g = threadIdx.x, q = g >> 6;
        float scl = (q == 2) ? TWOLOG2E : -LOG2E;
        float acc = bih[g] + bhh[g];
        const float* er = emb + ch * E;
        const float* wr = Wih + g * E;
        #pragma unroll
        for (int e = 0; e < E; ++e) acc = fmaf(er[e], wr[e], acc);
        xtab[ch * 256 + g] = acc * scl;
    } else if (bid < VOCAB + 64) {             // Wb = bf16(scaled Whh), [256][64]
        int i = (bid - VOCAB) * 256 + threadIdx.x;
        int q = i >> 12;                       // gate quarter of row (i>>6)
        float scl = (q == 2) ? TWOLOG2E : -LOG2E;
        Wb[i] = f2bf(Whh[i] * scl);
    } else {                                   // per-block length histogram
        int blk = bid - (VOCAB + 64);          // 0..255
        __shared__ int h[16];
        if (threadIdx.x < 16) h[threadIdx.x] = 0;
        __syncthreads();
        atomicAdd(&h[lengths[blk * 256 + threadIdx.x] - 1], 1);
        __syncthreads();
        if (threadIdx.x < 16) bh[blk * 16 + threadIdx.x] = h[threadIdx.x];
    }
}

// ---- K2: sort (bases recomputed per block from bh, then scatter) ----
__global__ void k_sort(const int* __restrict__ lengths, const int* __restrict__ bh,
                       int* __restrict__ perm) {
    __shared__ int lbh[4096];                  // bh copy, 16 KB
    __shared__ int pre[16], tot[16], gb[16], mybase[16], hh[16];
    const int t = threadIdx.x, B = blockIdx.x;
    for (int i = t; i < 4096; i += 256) lbh[i] = bh[i];
    if (t < 16) hh[t] = 0;
    __syncthreads();
    if (t < 16) {
        int s = 0;
        for (int B2 = 0; B2 < B; ++B2) s += lbh[B2 * 16 + t];
        int tt = s;
        for (int B2 = B; B2 < 256; ++B2) tt += lbh[B2 * 16 + t];
        pre[t] = s; tot[t] = tt;
    }
    __syncthreads();
    if (t == 0) { int a = 0; for (int i = 0; i < 16; ++i) { gb[i] = a; a += tot[i]; } }
    __syncthreads();
    if (t < 16) mybase[t] = gb[t] + pre[t];
    __syncthreads();
    int w = B * 256 + t;
    int b = lengths[w] - 1;
    int r = atomicAdd(&hh[b], 1);
    perm[mybase[b] + r] = w;
}

// ---- K3: main ----
__global__ __launch_bounds__(256, 2) void lstm_main(
    const ushort_t* __restrict__ Wb, const float* __restrict__ xtab,
    const int* __restrict__ chars, const int* __restrict__ lengths,
    const int* __restrict__ perm, float* __restrict__ out)
{
    __shared__ __align__(16) char Hlds_all[4][2048];
    char* Hbase = Hlds_all[threadIdx.x >> 6];

    const int lane = threadIdx.x & 63;
    const int w  = lane & 15;                  // word slot (MFMA N-col)
    const int lq = lane >> 4;                  // lane quad
    const int wave = (blockIdx.x << 2) + (threadIdx.x >> 6);   // 0..2047

    // A-fragments (weights): tile m covers gates m*16..m*16+15.
    bf16x8 a[16][2];
    #pragma unroll
    for (int m = 0; m < 16; ++m)
        #pragma unroll
        for (int kh = 0; kh < 2; ++kh)
            a[m][kh] = *reinterpret_cast<const bf16x8*>(Wb + ((m * 16 + w) * 64 + kh * 32 + lq * 8));

    // Swizzled per-wave LDS bounce offsets for H (write/read same involution).
    const int sw = (w & 7) << 4;
    const int base_w = w * 128;
    int wr_off[4], rd_off[2];
    #pragma unroll
    for (int b = 0; b < 4; ++b) wr_off[b] = base_w + ((b * 32 + lq * 8) ^ sw);
    #pragma unroll
    for (int kh = 0; kh < 2; ++kh) rd_off[kh] = base_w + ((kh * 64 + lq * 16) ^ sw);

    #pragma unroll 1
    for (int gi = 0; gi < 2; ++gi) {
        const int grp = gi ? (NGRP - 1 - wave) : wave;   // complementary pair: ~17 steps total
        const int wid = perm[grp * 16 + w];
        const int len = lengths[wid];
        int ml = len;                                    // group-max length over 16 slots
        ml = max(ml, __shfl_xor(ml, 1));
        ml = max(ml, __shfl_xor(ml, 2));
        ml = max(ml, __shfl_xor(ml, 4));
        ml = max(ml, __shfl_xor(ml, 8));
        const int maxl = __builtin_amdgcn_readfirstlane(ml);
        const int* chp = chars + wid * MAXL;

        float hreg[4][4], creg[4][4];
        #pragma unroll
        for (int b = 0; b < 4; ++b)
            #pragma unroll
            for (int r = 0; r < 4; ++r) { hreg[b][r] = 0.f; creg[b][r] = 0.f; }

        // rolling char prefetch: chA = char(t), chB = char(t+1)
        int chA = chp[0];
        int chB = chp[maxl > 1 ? 1 : 0];
        // preload all 16 xt tiles for t=0 from chA's row
        f32x4 xtb[2][4][2];                              // [half][q][bi]
        {
            const float* xr = xtab + chA * 256;
            #pragma unroll
            for (int bp = 0; bp < 2; ++bp)
                #pragma unroll
                for (int q = 0; q < 4; ++q)
                    #pragma unroll
                    for (int bi = 0; bi < 2; ++bi)
                        xtb[bp][q][bi] = *reinterpret_cast<const f32x4*>(xr + (q * 4 + bp * 2 + bi) * 16 + lq * 4);
        }

        bf16x8 Bc0, Bc1;                                 // B-fragments for current step (read at end of prev)

        #pragma unroll 1
        for (int t = 0; t < maxl; ++t) {
            const int tnn = (t + 2 < maxl) ? t + 2 : maxl - 1;
            const int chC = chp[tnn];                    // char(t+2), issue early
            const float* xrow_n = xtab + chB * 256;      // char(t+1) row
            const bool act = (t < len);

            #pragma unroll
            for (int bp = 0; bp < 2; ++bp) {
                // ---- MFMA: 8 tiles (gate-type q, unit-block b = bp*2+bi) ----
                f32x4 dd[4][2];
                #pragma unroll
                for (int q = 0; q < 4; ++q)
                    #pragma unroll
                    for (int bi = 0; bi < 2; ++bi)
                        dd[q][bi] = xtb[bp][q][bi];
                if (t > 0) {
                    #pragma unroll
                    for (int q = 0; q < 4; ++q)
                        #pragma unroll
                        for (int bi = 0; bi < 2; ++bi) {
                            dd[q][bi] = __builtin_amdgcn_mfma_f32_16x16x32_bf16(a[q * 4 + bp * 2 + bi][0], Bc0, dd[q][bi], 0, 0, 0);
                            dd[q][bi] = __builtin_amdgcn_mfma_f32_16x16x32_bf16(a[q * 4 + bp * 2 + bi][1], Bc1, dd[q][bi], 0, 0, 0);
                        }
                }
                // ---- prefetch next step's xt for this half ----
                #pragma unroll
                for (int q = 0; q < 4; ++q)
                    #pragma unroll
                    for (int bi = 0; bi < 2; ++bi)
                        xtb[bp][q][bi] = *reinterpret_cast<const f32x4*>(xrow_n + (q * 4 + bp * 2 + bi) * 16 + lq * 4);

                // ---- batched activations over 8 independent cells (bi, r) ----
                // d order: q=0:i', 1:f', 2:g', 3:o' (i,f,o scaled -log2e; g scaled 2log2e)
                float ui[2][4], uf[2][4], ug[2][4], uo[2][4];
                #pragma unroll
                for (int bi = 0; bi < 2; ++bi)
                    #pragma unroll
                    for (int r = 0; r < 4; ++r) ui[bi][r] = exp2_hw(dd[0][bi][r]);
                #pragma unroll
                for (int bi = 0; bi < 2; ++bi)
                    #pragma unroll
                    for (int r = 0; r < 4; ++r) uf[bi][r] = exp2_hw(dd[1][bi][r]);
                #pragma unroll
                for (int bi = 0; bi < 2; ++bi)
                    #pragma unroll
                    for (int r = 0; r < 4; ++r) ug[bi][r] = exp2_hw(dd[2][bi][r]);
                #pragma unroll
                for (int bi = 0; bi < 2; ++bi)
                    #pragma unroll
                    for (int r = 0; r < 4; ++r) uo[bi][r] = exp2_hw(dd[3][bi][r]);

                float igg[2][4], fg[2][4];
                #pragma unroll
                for (int bi = 0; bi < 2; ++bi)
                    #pragma unroll
                    for (int r = 0; r < 4; ++r)
                        igg[bi][r] = (ug[bi][r] - 1.f) * rcp_hw((1.f + ui[bi][r]) * (1.f + ug[bi][r]));
                #pragma unroll
                for (int bi = 0; bi < 2; ++bi)
                    #pragma unroll
                    for (int r = 0; r < 4; ++r) fg[bi][r] = rcp_hw(1.f + uf[bi][r]);

                float cnl[2][4];
                #pragma unroll
                for (int bi = 0; bi < 2; ++bi)
                    #pragma unroll
                    for (int r = 0; r < 4; ++r)
                        cnl[bi][r] = fmaf(fg[bi][r], creg[bp * 2 + bi][r], igg[bi][r]);

                float uc[2][4];
                #pragma unroll
                for (int bi = 0; bi < 2; ++bi)
                    #pragma unroll
                    for (int r = 0; r < 4; ++r) uc[bi][r] = exp2_hw(cnl[bi][r] * TWOLOG2E);

                #pragma unroll
                for (int bi = 0; bi < 2; ++bi) {
                    const int b = bp * 2 + bi;
                    #pragma unroll
                    for (int r = 0; r < 4; ++r) {
                        float hn = (uc[bi][r] - 1.f) * rcp_hw((1.f + uo[bi][r]) * (1.f + uc[bi][r]));
                        creg[b][r] = act ? cnl[bi][r] : creg[b][r];
                        hreg[b][r] = act ? hn : hreg[b][r];
                    }
                    uint_t lo = (uint_t)f2bf(hreg[b][0]) | ((uint_t)f2bf(hreg[b][1]) << 16);
                    uint_t hi = (uint_t)f2bf(hreg[b][2]) | ((uint_t)f2bf(hreg[b][3]) << 16);
                    *reinterpret_cast<uint2*>(Hbase + wr_off[b]) = make_uint2(lo, hi);
                }
            }

            // ---- end-of-step: read B for t+1 (hides LDS latency under next MFMAs) ----
            asm volatile("s_waitcnt lgkmcnt(0)" ::: "memory");   // H writes done
            Bc0 = *reinterpret_cast<const bf16x8*>(Hbase + rd_off[0]);
            Bc1 = *reinterpret_cast<const bf16x8*>(Hbase + rd_off[1]);

            chA = chB;
            chB = chC;
        }

        #pragma unroll
        for (int b = 0; b < 4; ++b) {
            f32x4 o;
            #pragma unroll
            for (int r = 0; r < 4; ++r) o[r] = hreg[b][r];
            *reinterpret_cast<f32x4*>(out + wid * 64 + b * 16 + lq * 4) = o;
        }
    }
}

extern "C" void kernel_launch(void* const* d_in, const int* in_sizes, int n_in,
                              void* d_out, int out_size, void* d_ws, size_t ws_size,
                              hipStream_t stream) {
    const float* emb = (const float*)d_in[0];
    const float* Wih = (const float*)d_in[1];
    const float* Whh = (const float*)d_in[2];
    const float* bih = (const float*)d_in[3];
    const float* bhh = (const float*)d_in[4];
    const int* chars = (const int*)d_in[5];
    const int* lens  = (const int*)d_in[6];
    float* out = (float*)d_out;

    float*    xtab = (float*)d_ws;              // 25600 f32 = 100 KB
    ushort_t* Wb   = (ushort_t*)(xtab + 25600); // 16384 bf16 = 32 KB
    int*      bh   = (int*)(Wb + 16384);        // 256*16
    int*      perm = bh + 4096;                 // 65536

    prep_all<<<VOCAB + 64 + 256, 256, 0, stream>>>(emb, Wih, Whh, bih, bhh, lens, xtab, Wb, bh);
    k_sort<<<256, 256, 0, stream>>>(lens, bh, perm);

    // 512 blocks x 4 waves = 2048 waves; wave g does groups g and 4095-g (~17 steps)
    lstm_main<<<512, 256, 0, stream>>>(Wb, xtab, chars, lens, perm, out);
}

// Round 9
// 172.982 us; speedup vs baseline: 1.1719x; 1.1719x over previous
//
#include <hip/hip_runtime.h>
#include <hip/hip_bf16.h>

// Char-LSTM via MFMA, round 9.
// r8 failed via scratch spills (xtb dbuf alone = 128 VGPR; FETCH 38MB).
// r7 retro-insight: compiler reloads A-fragments from L2 each step anyway.
// This round: split each 16-word group across 2 COOPERATING WAVES (wave ws
// owns units ws*32..ws*32+31): halves trans work per wave (64/step) and
// doubles wave count (4096 waves -> up to 4/SIMD) to cover trans-chain
// bubbles with TLP. H exchanged per step via double-buffered 2KB LDS tile +
// __syncthreads (2-wave block). Complementary pair (g, 4095-g) per block
// keeps every block at ~17-18 steps regardless of SIMD assignment.

#define VOCAB 100
#define E     32
#define NW    65536
#define MAXL  16
#define NGRP  4096   // NW/16

typedef __bf16 bf16x8 __attribute__((ext_vector_type(8)));
typedef float  f32x4  __attribute__((ext_vector_type(4)));
typedef unsigned short ushort_t;
typedef unsigned int uint_t;

#define LOG2E    1.4426950408889634f
#define TWOLOG2E 2.8853900817779268f

__device__ __forceinline__ ushort_t f2bf(float x) {
    union { __hip_bfloat16 b; ushort_t u; } cv;
    cv.b = __float2bfloat16(x);
    return cv.u;
}
__device__ __forceinline__ float exp2_hw(float x) { return __builtin_amdgcn_exp2f(x); }
__device__ __forceinline__ float rcp_hw(float x)  { return __builtin_amdgcn_rcpf(x); }

// ---- K1: xtab [100][256] f32 (scaled), Wb [256][64] bf16 (scaled), hist bh[256][16] ----
__global__ void prep_all(const float* __restrict__ emb, const float* __restrict__ Wih,
                         const float* __restrict__ Whh, const float* __restrict__ bih,
                         const float* __restrict__ bhh, const int* __restrict__ lengths,
                         float* __restrict__ xtab, ushort_t* __restrict__ Wb,
                         int* __restrict__ bh) {
    int bid = blockIdx.x;
    if (bid < VOCAB) {                         // xtab row: g = q*64+u (torch row order)
        int ch = bid, g = threadIdx.x, q = g >> 6;
        float scl = (q == 2) ? TWOLOG2E : -LOG2E;
        float acc = bih[g] + bhh[g];
        const float* er = emb + ch * E;
        const float* wr = Wih + g * E;
        #pragma unroll
        for (int e = 0; e < E; ++e) acc = fmaf(er[e], wr[e], acc);
        xtab[ch * 256 + g] = acc * scl;
    } else if (bid < VOCAB + 64) {             // Wb = bf16(scaled Whh), [256][64]
        int i = (bid - VOCAB) * 256 + threadIdx.x;
        int q = i >> 12;                       // gate quarter of row (i>>6)
        float scl = (q == 2) ? TWOLOG2E : -LOG2E;
        Wb[i] = f2bf(Whh[i] * scl);
    } else {                                   // per-block length histogram
        int blk = bid - (VOCAB + 64);          // 0..255
        __shared__ int h[16];
        if (threadIdx.x < 16) h[threadIdx.x] = 0;
        __syncthreads();
        atomicAdd(&h[lengths[blk * 256 + threadIdx.x] - 1], 1);
        __syncthreads();
        if (threadIdx.x < 16) bh[blk * 16 + threadIdx.x] = h[threadIdx.x];
    }
}

// ---- K2: sort (bases recomputed per block from bh, then scatter) ----
__global__ void k_sort(const int* __restrict__ lengths, const int* __restrict__ bh,
                       int* __restrict__ perm) {
    __shared__ int lbh[4096];                  // bh copy, 16 KB
    __shared__ int pre[16], tot[16], gb[16], mybase[16], hh[16];
    const int t = threadIdx.x, B = blockIdx.x;
    for (int i = t; i < 4096; i += 256) lbh[i] = bh[i];
    if (t < 16) hh[t] = 0;
    __syncthreads();
    if (t < 16) {
        int s = 0;
        for (int B2 = 0; B2 < B; ++B2) s += lbh[B2 * 16 + t];
        int tt = s;
        for (int B2 = B; B2 < 256; ++B2) tt += lbh[B2 * 16 + t];
        pre[t] = s; tot[t] = tt;
    }
    __syncthreads();
    if (t == 0) { int a = 0; for (int i = 0; i < 16; ++i) { gb[i] = a; a += tot[i]; } }
    __syncthreads();
    if (t < 16) mybase[t] = gb[t] + pre[t];
    __syncthreads();
    int w = B * 256 + t;
    int b = lengths[w] - 1;
    int r = atomicAdd(&hh[b], 1);
    perm[mybase[b] + r] = w;
}

// ---- K3: main (2 waves per block, each owns 32 hidden units of the group) ----
__global__ __launch_bounds__(128, 3) void lstm_main(
    const ushort_t* __restrict__ Wb, const float* __restrict__ xtab,
    const int* __restrict__ chars, const int* __restrict__ lengths,
    const int* __restrict__ perm, float* __restrict__ out)
{
    __shared__ __align__(16) char Hlds[2][2048];   // double-buffered H[16w][64u] bf16

    const int tid  = threadIdx.x;
    const int ws   = tid >> 6;                 // wave slot: unit half 0/1
    const int lane = tid & 63;
    const int w    = lane & 15;                // word slot (MFMA N-col)
    const int lq   = lane >> 4;                // lane quad

    // A-fragments: this wave's 8 M-tiles m = q*4 + ws*2 + bi (gate q, unit block)
    bf16x8 a[4][2][2];                         // [q][bi][kh]
    #pragma unroll
    for (int q = 0; q < 4; ++q)
        #pragma unroll
        for (int bi = 0; bi < 2; ++bi)
            #pragma unroll
            for (int kh = 0; kh < 2; ++kh) {
                const int m = q * 4 + ws * 2 + bi;
                a[q][bi][kh] = *reinterpret_cast<const bf16x8*>(Wb + ((m * 16 + w) * 64 + kh * 32 + lq * 8));
            }

    // Swizzled LDS offsets (same involution on write and read)
    const int sw = (w & 7) << 4;
    const int base_w = w * 128;
    int wr_off[2], rd_off[2];
    #pragma unroll
    for (int bi = 0; bi < 2; ++bi) wr_off[bi] = base_w + ((((ws * 2 + bi) * 32) + lq * 8) ^ sw);
    #pragma unroll
    for (int kh = 0; kh < 2; ++kh) rd_off[kh] = base_w + ((kh * 64 + lq * 16) ^ sw);

    #pragma unroll 1
    for (int gi = 0; gi < 2; ++gi) {
        const int grp = gi ? (NGRP - 1 - (int)blockIdx.x) : (int)blockIdx.x;
        const int wid = perm[grp * 16 + w];
        const int len = lengths[wid];
        int ml = len;                          // group-max length over the 16 slots
        ml = max(ml, __shfl_xor(ml, 1));
        ml = max(ml, __shfl_xor(ml, 2));
        ml = max(ml, __shfl_xor(ml, 4));
        ml = max(ml, __shfl_xor(ml, 8));
        const int maxl = __builtin_amdgcn_readfirstlane(ml);
        const int* chp = chars + wid * MAXL;

        float hreg[2][4], creg[2][4];
        #pragma unroll
        for (int bi = 0; bi < 2; ++bi)
            #pragma unroll
            for (int r = 0; r < 4; ++r) { hreg[bi][r] = 0.f; creg[bi][r] = 0.f; }

        bf16x8 B0 = {}, B1 = {};
        int ch = chp[0];

        #pragma unroll 1
        for (int t = 0; t < maxl; ++t) {
            const int chN = chp[(t + 1 < maxl) ? t + 1 : t];   // rolling prefetch
            const float* xr = xtab + ch * 256;
            const bool act = (t < len);

            // gates init from xt table (per-lane gather, word w's row)
            f32x4 dd[4][2];
            #pragma unroll
            for (int q = 0; q < 4; ++q)
                #pragma unroll
                for (int bi = 0; bi < 2; ++bi)
                    dd[q][bi] = *reinterpret_cast<const f32x4*>(xr + (q * 4 + ws * 2 + bi) * 16 + lq * 4);

            if (t > 0) {
                #pragma unroll
                for (int q = 0; q < 4; ++q)
                    #pragma unroll
                    for (int bi = 0; bi < 2; ++bi) {
                        dd[q][bi] = __builtin_amdgcn_mfma_f32_16x16x32_bf16(a[q][bi][0], B0, dd[q][bi], 0, 0, 0);
                        dd[q][bi] = __builtin_amdgcn_mfma_f32_16x16x32_bf16(a[q][bi][1], B1, dd[q][bi], 0, 0, 0);
                    }
            }

            // batched activations over 8 independent cells (bi, r)
            // d order q=0:i', 1:f', 2:g', 3:o' (i,f,o scaled -log2e; g scaled 2log2e)
            float ui[2][4], uf[2][4], ug[2][4], uo[2][4];
            #pragma unroll
            for (int bi = 0; bi < 2; ++bi)
                #pragma unroll
                for (int r = 0; r < 4; ++r) ui[bi][r] = exp2_hw(dd[0][bi][r]);
            #pragma unroll
            for (int bi = 0; bi < 2; ++bi)
                #pragma unroll
                for (int r = 0; r < 4; ++r) uf[bi][r] = exp2_hw(dd[1][bi][r]);
            #pragma unroll
            for (int bi = 0; bi < 2; ++bi)
                #pragma unroll
                for (int r = 0; r < 4; ++r) ug[bi][r] = exp2_hw(dd[2][bi][r]);
            #pragma unroll
            for (int bi = 0; bi < 2; ++bi)
                #pragma unroll
                for (int r = 0; r < 4; ++r) uo[bi][r] = exp2_hw(dd[3][bi][r]);

            float igg[2][4], fg[2][4];
            #pragma unroll
            for (int bi = 0; bi < 2; ++bi)
                #pragma unroll
                for (int r = 0; r < 4; ++r)
                    igg[bi][r] = (ug[bi][r] - 1.f) * rcp_hw((1.f + ui[bi][r]) * (1.f + ug[bi][r]));
            #pragma unroll
            for (int bi = 0; bi < 2; ++bi)
                #pragma unroll
                for (int r = 0; r < 4; ++r) fg[bi][r] = rcp_hw(1.f + uf[bi][r]);

            float cnl[2][4], uc[2][4];
            #pragma unroll
            for (int bi = 0; bi < 2; ++bi)
                #pragma unroll
                for (int r = 0; r < 4; ++r)
                    cnl[bi][r] = fmaf(fg[bi][r], creg[bi][r], igg[bi][r]);
            #pragma unroll
            for (int bi = 0; bi < 2; ++bi)
                #pragma unroll
                for (int r = 0; r < 4; ++r) uc[bi][r] = exp2_hw(cnl[bi][r] * TWOLOG2E);

            char* Hb = Hlds[t & 1];
            #pragma unroll
            for (int bi = 0; bi < 2; ++bi) {
                #pragma unroll
                for (int r = 0; r < 4; ++r) {
                    float hn = (uc[bi][r] - 1.f) * rcp_hw((1.f + uo[bi][r]) * (1.f + uc[bi][r]));
                    creg[bi][r] = act ? cnl[bi][r] : creg[bi][r];
                    hreg[bi][r] = act ? hn : hreg[bi][r];
                }
                uint_t lo = (uint_t)f2bf(hreg[bi][0]) | ((uint_t)f2bf(hreg[bi][1]) << 16);
                uint_t hi = (uint_t)f2bf(hreg[bi][2]) | ((uint_t)f2bf(hreg[bi][3]) << 16);
                *reinterpret_cast<uint2*>(Hb + wr_off[bi]) = make_uint2(lo, hi);
            }

            asm volatile("s_waitcnt lgkmcnt(0)" ::: "memory");  // H writes drained
            __syncthreads();                                    // co-wave sync
            B0 = *reinterpret_cast<const bf16x8*>(Hb + rd_off[0]);
            B1 = *reinterpret_cast<const bf16x8*>(Hb + rd_off[1]);
            ch = chN;
        }

        // output: this wave's 2 unit-blocks (coalesced f32x4 per word)
        #pragma unroll
        for (int bi = 0; bi < 2; ++bi) {
            f32x4 o;
            #pragma unroll
            for (int r = 0; r < 4; ++r) o[r] = hreg[bi][r];
            *reinterpret_cast<f32x4*>(out + wid * 64 + (ws * 2 + bi) * 16 + lq * 4) = o;
        }
        __syncthreads();                       // isolate gi iterations (buffer reuse)
    }
}

extern "C" void kernel_launch(void* const* d_in, const int* in_sizes, int n_in,
                              void* d_out, int out_size, void* d_ws, size_t ws_size,
                              hipStream_t stream) {
    const float* emb = (const float*)d_in[0];
    const float* Wih = (const float*)d_in[1];
    const float* Whh = (const float*)d_in[2];
    const float* bih = (const float*)d_in[3];
    const float* bhh = (const float*)d_in[4];
    const int* chars = (const int*)d_in[5];
    const int* lens  = (const int*)d_in[6];
    float* out = (float*)d_out;

    float*    xtab = (float*)d_ws;              // 25600 f32 = 100 KB
    ushort_t* Wb   = (ushort_t*)(xtab + 25600); // 16384 bf16 = 32 KB
    int*      bh   = (int*)(Wb + 16384);        // 256*16
    int*      perm = bh + 4096;                 // 65536

    prep_all<<<VOCAB + 64 + 256, 256, 0, stream>>>(emb, Wih, Whh, bih, bhh, lens, xtab, Wb, bh);
    k_sort<<<256, 256, 0, stream>>>(lens, bh, perm);

    // 2048 blocks x 2 waves; block b handles groups b and 4095-b (~17-18 steps)
    lstm_main<<<2048, 128, 0, stream>>>(Wb, xtab, chars, lens, perm, out);
}